// Round 1
// baseline (255.714 us; speedup 1.0000x reference)
//
#include <hip/hip_runtime.h>
#include <hip/hip_bf16.h>

// MPNNConv: out = segment_sum(relu([h[r]|h[c]|ef] @ W1 + b1) @ W2 + b2, rows)
// Restructured:
//   s[n]    = h[n] @ W1[0:128,:] + b1                  (small GEMM, f32 out)
//   Hsum[n] = sum_{e: rows[e]=n} relu(s[n] + [h[cols[e]]|ef[e]] @ W1[128:288,:])
//   out[n]  = Hsum[n] @ W2 + deg[n]*b2                 (small GEMM)
// CSR built on-device per call (deterministic given inputs up to fp sum order).

typedef __attribute__((ext_vector_type(8))) short bf16x8;
typedef __attribute__((ext_vector_type(4))) float f32x4;

#define ND 128   // node dim
#define ED 32    // edge dim
#define KR 160   // reduced per-edge K (128 + 32)

__device__ __forceinline__ short f2bf(float x) {
  unsigned int u = __float_as_uint(x);
  unsigned int r = (u + 0x7FFFu + ((u >> 16) & 1u)) >> 16;
  return (short)r;
}

__device__ __forceinline__ int load_idx(const void* ei, long long i, int is64) {
  return is64 ? (int)((const long long*)ei)[i] : ((const int*)ei)[i];
}

// --- detect int64 vs int32 edge_index (values < 2^31 -> high words all 0) ---
__global__ void detect_kernel(const unsigned int* ei, int* flag) {
  if (threadIdx.x == 0 && blockIdx.x == 0) {
    int is64 = 1;
    for (int i = 0; i < 16; ++i)
      if (ei[2 * i + 1] != 0u) is64 = 0;
    flag[0] = is64;
  }
}

// --- bf16 conversions + weight transposes ---
__global__ void prep_kernel(const float* __restrict__ h, const float* __restrict__ W1,
                            const float* __restrict__ W2, short* __restrict__ hb,
                            short* __restrict__ w1t_top, short* __restrict__ w1ts,
                            short* __restrict__ w2t, int NH) {
  int t = blockIdx.x * blockDim.x + threadIdx.x;
  if (t < NH) hb[t] = f2bf(h[t]);
  if (t < 128 * 128) {
    int n = t >> 7, k = t & 127;
    w1t_top[t] = f2bf(W1[k * 128 + n]);   // W1t_top[n][k] = W1[k][n], k<128
    w2t[t]     = f2bf(W2[k * 128 + n]);   // W2t[n][k]    = W2[k][n]
  }
  if (t < 128 * KR) {
    int n = t / KR, k = t - n * KR;
    w1ts[t] = f2bf(W1[(128 + k) * 128 + n]);  // W1ts[n][k] = W1[128+k][n]
  }
}

__global__ void hist_kernel(const void* ei, const int* __restrict__ flag,
                            int* __restrict__ counts, int E) {
  int e = blockIdx.x * blockDim.x + threadIdx.x;
  if (e >= E) return;
  atomicAdd(&counts[load_idx(ei, e, flag[0])], 1);
}

// single-block exclusive scan of counts[0..n) -> row_ptr[0..n]
__global__ void scan_kernel(const int* __restrict__ counts, int* __restrict__ row_ptr, int n) {
  __shared__ int wsum[16];
  __shared__ int base_s;
  int tid = threadIdx.x;
  int lane = tid & 63, w = tid >> 6;
  if (tid == 0) { base_s = 0; row_ptr[0] = 0; }
  __syncthreads();
  for (int start = 0; start < n; start += 1024) {
    int i = start + tid;
    int v = (i < n) ? counts[i] : 0;
    #pragma unroll
    for (int d = 1; d < 64; d <<= 1) {
      int t = __shfl_up(v, d);
      if (lane >= d) v += t;
    }
    if (lane == 63) wsum[w] = v;
    __syncthreads();
    if (w == 0) {
      int x = (lane < 16) ? wsum[lane] : 0;
      #pragma unroll
      for (int d = 1; d < 16; d <<= 1) {
        int t = __shfl_up(x, d);
        if (lane >= d) x += t;
      }
      if (lane < 16) wsum[lane] = x;
    }
    __syncthreads();
    int waveoff = (w == 0) ? 0 : wsum[w - 1];
    int total = wsum[15];
    if (i < n) row_ptr[i + 1] = base_s + waveoff + v;
    __syncthreads();
    if (tid == 0) base_s += total;
    __syncthreads();
  }
}

__global__ void scatter_kernel(const void* ei, const int* __restrict__ flag,
                               const int* __restrict__ row_ptr, int* __restrict__ cur,
                               int* __restrict__ elist, int* __restrict__ ccol, int E) {
  int e = blockIdx.x * blockDim.x + threadIdx.x;
  if (e >= E) return;
  int f = flag[0];
  int r = load_idx(ei, e, f);
  int c = load_idx(ei, (long long)E + e, f);
  int pos = row_ptr[r] + atomicAdd(&cur[r], 1);
  elist[pos] = e;
  ccol[pos] = c;
}

// --- s = h @ W1[0:128,:] + b1 : one wave computes 64 rows x 128 cols ---
__global__ __launch_bounds__(64) void s_kernel(const short* __restrict__ hb,
                                               const short* __restrict__ w1t,
                                               const float* __restrict__ b1,
                                               float* __restrict__ s, int N) {
  int lane = threadIdx.x, li = lane & 15, lg = lane >> 4;
  int base = blockIdx.x * 64;
  float breg[8];
  #pragma unroll
  for (int nt = 0; nt < 8; ++nt) breg[nt] = b1[nt * 16 + li];
  f32x4 acc[4][8];
  #pragma unroll
  for (int m = 0; m < 4; ++m)
    #pragma unroll
    for (int nt = 0; nt < 8; ++nt) acc[m][nt] = (f32x4){0.f, 0.f, 0.f, 0.f};
  int rowm[4];
  #pragma unroll
  for (int m = 0; m < 4; ++m) {
    int r = base + m * 16 + li;
    rowm[m] = r < N ? r : N - 1;
  }
  #pragma unroll
  for (int kc = 0; kc < 4; ++kc) {
    bf16x8 a[4];
    #pragma unroll
    for (int m = 0; m < 4; ++m)
      a[m] = *(const bf16x8*)(hb + rowm[m] * ND + kc * 32 + lg * 8);
    #pragma unroll
    for (int nt = 0; nt < 8; ++nt) {
      bf16x8 b = *(const bf16x8*)(w1t + (nt * 16 + li) * 128 + kc * 32 + lg * 8);
      #pragma unroll
      for (int m = 0; m < 4; ++m)
        acc[m][nt] = __builtin_amdgcn_mfma_f32_16x16x32_bf16(a[m], b, acc[m][nt], 0, 0, 0);
    }
  }
  #pragma unroll
  for (int m = 0; m < 4; ++m)
    #pragma unroll
    for (int r = 0; r < 4; ++r) {
      int row = base + m * 16 + lg * 4 + r;
      if (row < N) {
        #pragma unroll
        for (int nt = 0; nt < 8; ++nt)
          s[row * 128 + nt * 16 + li] = acc[m][nt][r] + breg[nt];
      }
    }
}

// --- layer 1 + segment reduction: one wave per node ---
__global__ __launch_bounds__(64) void layer1_kernel(
    const short* __restrict__ hb, const float* __restrict__ ef,
    const short* __restrict__ w1ts, const float* __restrict__ sarr,
    const int* __restrict__ row_ptr, const int* __restrict__ elist,
    const int* __restrict__ ccol, float* __restrict__ hsum, int N) {
  int node = blockIdx.x;
  int lane = threadIdx.x, li = lane & 15, lg = lane >> 4;
  int rp = row_ptr[node], rpe = row_ptr[node + 1];
  int deg = rpe - rp;
  float sreg[8];
  #pragma unroll
  for (int nt = 0; nt < 8; ++nt) sreg[nt] = sarr[node * 128 + nt * 16 + li];
  float psum[8] = {0.f, 0.f, 0.f, 0.f, 0.f, 0.f, 0.f, 0.f};
  int ntiles = (deg + 15) >> 4;
  int ngroups = (ntiles + 3) >> 2;
  for (int g = 0; g < ngroups; ++g) {
    int mact = ntiles - g * 4;
    if (mact > 4) mact = 4;
    int eid[4] = {0, 0, 0, 0}, col[4] = {0, 0, 0, 0};
    #pragma unroll
    for (int m = 0; m < 4; ++m)
      if (m < mact) {
        int p = rp + (g * 4 + m) * 16 + li;
        if (p > rpe - 1) p = rpe - 1;  // clamp (masked at psum stage)
        eid[m] = elist[p];
        col[m] = ccol[p];
      }
    f32x4 acc[4][8];
    #pragma unroll
    for (int m = 0; m < 4; ++m)
      #pragma unroll
      for (int nt = 0; nt < 8; ++nt) acc[m][nt] = (f32x4){0.f, 0.f, 0.f, 0.f};
    #pragma unroll
    for (int kc = 0; kc < 5; ++kc) {
      bf16x8 a[4];
      #pragma unroll
      for (int m = 0; m < 4; ++m)
        if (m < mact) {
          if (kc < 4) {
            a[m] = *(const bf16x8*)(hb + col[m] * ND + kc * 32 + lg * 8);
          } else {
            f32x4 f0 = *(const f32x4*)(ef + eid[m] * ED + lg * 8);
            f32x4 f1 = *(const f32x4*)(ef + eid[m] * ED + lg * 8 + 4);
            bf16x8 t;
            #pragma unroll
            for (int j = 0; j < 4; ++j) { t[j] = f2bf(f0[j]); t[4 + j] = f2bf(f1[j]); }
            a[m] = t;
          }
        }
      #pragma unroll
      for (int nt = 0; nt < 8; ++nt) {
        bf16x8 b = *(const bf16x8*)(w1ts + (nt * 16 + li) * KR + kc * 32 + lg * 8);
        #pragma unroll
        for (int m = 0; m < 4; ++m)
          if (m < mact)
            acc[m][nt] = __builtin_amdgcn_mfma_f32_16x16x32_bf16(a[m], b, acc[m][nt], 0, 0, 0);
      }
    }
    #pragma unroll
    for (int m = 0; m < 4; ++m)
      if (m < mact)
        #pragma unroll
        for (int nt = 0; nt < 8; ++nt)
          #pragma unroll
          for (int r = 0; r < 4; ++r) {
            int slot = (g * 4 + m) * 16 + lg * 4 + r;
            float v = acc[m][nt][r] + sreg[nt];
            v = v > 0.f ? v : 0.f;
            if (slot < deg) psum[nt] += v;
          }
  }
  #pragma unroll
  for (int nt = 0; nt < 8; ++nt) {
    psum[nt] += __shfl_xor(psum[nt], 16);
    psum[nt] += __shfl_xor(psum[nt], 32);
  }
  if (lane < 16) {
    #pragma unroll
    for (int nt = 0; nt < 8; ++nt) hsum[node * 128 + nt * 16 + lane] = psum[nt];
  }
}

// --- out = Hsum @ W2 + deg*b2 ---
__global__ __launch_bounds__(64) void out_kernel(const float* __restrict__ hsum,
                                                 const short* __restrict__ w2t,
                                                 const float* __restrict__ b2,
                                                 const int* __restrict__ row_ptr,
                                                 float* __restrict__ out, int N) {
  int lane = threadIdx.x, li = lane & 15, lg = lane >> 4;
  int base = blockIdx.x * 64;
  float breg[8];
  #pragma unroll
  for (int nt = 0; nt < 8; ++nt) breg[nt] = b2[nt * 16 + li];
  f32x4 acc[4][8];
  #pragma unroll
  for (int m = 0; m < 4; ++m)
    #pragma unroll
    for (int nt = 0; nt < 8; ++nt) acc[m][nt] = (f32x4){0.f, 0.f, 0.f, 0.f};
  int rowm[4];
  #pragma unroll
  for (int m = 0; m < 4; ++m) {
    int r = base + m * 16 + li;
    rowm[m] = r < N ? r : N - 1;
  }
  #pragma unroll
  for (int kc = 0; kc < 4; ++kc) {
    bf16x8 a[4];
    #pragma unroll
    for (int m = 0; m < 4; ++m) {
      f32x4 f0 = *(const f32x4*)(hsum + rowm[m] * 128 + kc * 32 + lg * 8);
      f32x4 f1 = *(const f32x4*)(hsum + rowm[m] * 128 + kc * 32 + lg * 8 + 4);
      bf16x8 t;
      #pragma unroll
      for (int j = 0; j < 4; ++j) { t[j] = f2bf(f0[j]); t[4 + j] = f2bf(f1[j]); }
      a[m] = t;
    }
    #pragma unroll
    for (int nt = 0; nt < 8; ++nt) {
      bf16x8 b = *(const bf16x8*)(w2t + (nt * 16 + li) * 128 + kc * 32 + lg * 8);
      #pragma unroll
      for (int m = 0; m < 4; ++m)
        acc[m][nt] = __builtin_amdgcn_mfma_f32_16x16x32_bf16(a[m], b, acc[m][nt], 0, 0, 0);
    }
  }
  #pragma unroll
  for (int m = 0; m < 4; ++m)
    #pragma unroll
    for (int r = 0; r < 4; ++r) {
      int row = base + m * 16 + lg * 4 + r;
      if (row < N) {
        int dg = row_ptr[row + 1] - row_ptr[row];
        #pragma unroll
        for (int nt = 0; nt < 8; ++nt)
          out[row * 128 + nt * 16 + li] = acc[m][nt][r] + (float)dg * breg[nt];
      }
    }
}

extern "C" void kernel_launch(void* const* d_in, const int* in_sizes, int n_in,
                              void* d_out, int out_size, void* d_ws, size_t ws_size,
                              hipStream_t stream) {
  const float* h  = (const float*)d_in[0];
  const void*  ei = d_in[1];
  const float* ef = (const float*)d_in[2];
  const float* W1 = (const float*)d_in[4];
  const float* b1 = (const float*)d_in[5];
  const float* W2 = (const float*)d_in[6];
  const float* b2 = (const float*)d_in[7];
  float* out = (float*)d_out;
  int N = in_sizes[0] / ND;
  int E = in_sizes[2] / ED;

  char* ws = (char*)d_ws;
  size_t off = 0;
  auto alloc = [&](size_t bytes) {
    size_t o = off;
    off = (off + bytes + 255) & ~(size_t)255;
    return o;
  };
  int*   flag    = (int*)(ws + alloc(4));
  int*   counts  = (int*)(ws + alloc((size_t)N * 4));
  int*   cur     = (int*)(ws + alloc((size_t)N * 4));
  int*   row_ptr = (int*)(ws + alloc((size_t)(N + 1) * 4));
  int*   elist   = (int*)(ws + alloc((size_t)E * 4));
  int*   ccol    = (int*)(ws + alloc((size_t)E * 4));
  short* hb      = (short*)(ws + alloc((size_t)N * ND * 2));
  short* w1t_top = (short*)(ws + alloc(128 * 128 * 2));
  short* w1ts    = (short*)(ws + alloc(128 * KR * 2));
  short* w2t     = (short*)(ws + alloc(128 * 128 * 2));
  float* sarr    = (float*)(ws + alloc((size_t)N * 128 * 4));
  float* hsumb   = (float*)(ws + alloc((size_t)N * 128 * 4));

  hipMemsetAsync(counts, 0, (size_t)N * 4, stream);
  hipMemsetAsync(cur, 0, (size_t)N * 4, stream);
  detect_kernel<<<1, 64, 0, stream>>>((const unsigned int*)ei, flag);
  int NH = N * ND;
  prep_kernel<<<(NH + 255) / 256, 256, 0, stream>>>(h, W1, W2, hb, w1t_top, w1ts, w2t, NH);
  hist_kernel<<<(E + 255) / 256, 256, 0, stream>>>(ei, flag, counts, E);
  scan_kernel<<<1, 1024, 0, stream>>>(counts, row_ptr, N);
  scatter_kernel<<<(E + 255) / 256, 256, 0, stream>>>(ei, flag, row_ptr, cur, elist, ccol, E);
  s_kernel<<<(N + 63) / 64, 64, 0, stream>>>(hb, w1t_top, b1, sarr, N);
  layer1_kernel<<<N, 64, 0, stream>>>(hb, ef, w1ts, sarr, row_ptr, elist, ccol, hsumb, N);
  out_kernel<<<(N + 63) / 64, 64, 0, stream>>>(hsumb, w2t, b2, row_ptr, out, N);
}

// Round 2
// 204.346 us; speedup vs baseline: 1.2514x; 1.2514x over previous
//
#include <hip/hip_runtime.h>
#include <hip/hip_bf16.h>

// MPNNConv restructured:
//   sg[n] = h[n] @ [W1top | W1mid] (+b1 on s half)   -> s = sg[:,0:128], g = sg[:,128:256]
//   Hsum[n] = sum_{e: rows[e]=n} relu(s[n] + g[cols[e]] + ef[e] @ W1e)   (K=32 MFMA only)
//   out[n]  = Hsum[n] @ W2 + deg[n]*b2
// CSR built on-device per call.

typedef __attribute__((ext_vector_type(8))) short bf16x8;
typedef __attribute__((ext_vector_type(4))) float f32x4;

#define ND 128
#define ED 32

__device__ __forceinline__ short f2bf(float x) {
  unsigned int u = __float_as_uint(x);
  unsigned int r = (u + 0x7FFFu + ((u >> 16) & 1u)) >> 16;
  return (short)r;
}

__device__ __forceinline__ int load_idx(const void* ei, long long i, int is64) {
  return is64 ? (int)((const long long*)ei)[i] : ((const int*)ei)[i];
}

// --- detect int64 vs int32 edge_index ---
__global__ void detect_kernel(const unsigned int* ei, int* flag) {
  if (threadIdx.x == 0 && blockIdx.x == 0) {
    int is64 = 1;
    for (int i = 0; i < 16; ++i)
      if (ei[2 * i + 1] != 0u) is64 = 0;
    flag[0] = is64;
  }
}

// --- weight transposes / fragment pre-layouts (bf16) ---
__global__ void prep_kernel(const float* __restrict__ W1, const float* __restrict__ W2,
                            short* __restrict__ w12t, short* __restrict__ w1eA,
                            short* __restrict__ w2t) {
  int t = blockIdx.x * blockDim.x + threadIdx.x;
  if (t < 256 * 128) {  // w12t[n'][k]: n'<128 -> W1[k][n'] ; n'>=128 -> W1[128+k][n'-128]
    int np = t >> 7, k = t & 127;
    float v = (np < 128) ? W1[k * 128 + np] : W1[(128 + k) * 128 + (np - 128)];
    w12t[t] = f2bf(v);
  }
  if (t < 128 * 128) {  // w2t[n][k] = W2[k][n]
    int n = t >> 7, k = t & 127;
    w2t[t] = f2bf(W2[k * 128 + n]);
  }
  if (t < 8 * 64 * 8) { // w1eA[nt][lane][j] = W1[256 + lg*8+j][nt*16+li]  (A-frag, A=W1e^T)
    int nt = t >> 9, lane = (t >> 3) & 63, j = t & 7;
    int li = lane & 15, lg = lane >> 4;
    w1eA[t] = f2bf(W1[(256 + lg * 8 + j) * 128 + nt * 16 + li]);
  }
}

__global__ void hist_kernel(const void* ei, const int* __restrict__ flag,
                            int* __restrict__ counts, int E) {
  int e = blockIdx.x * blockDim.x + threadIdx.x;
  if (e >= E) return;
  atomicAdd(&counts[load_idx(ei, e, flag[0])], 1);
}

// single-block exclusive scan of counts[0..n) -> row_ptr[0..n]
__global__ void scan_kernel(const int* __restrict__ counts, int* __restrict__ row_ptr, int n) {
  __shared__ int wsum[16];
  __shared__ int base_s;
  int tid = threadIdx.x;
  int lane = tid & 63, w = tid >> 6;
  if (tid == 0) { base_s = 0; row_ptr[0] = 0; }
  __syncthreads();
  for (int start = 0; start < n; start += 1024) {
    int i = start + tid;
    int v = (i < n) ? counts[i] : 0;
    #pragma unroll
    for (int d = 1; d < 64; d <<= 1) {
      int t = __shfl_up(v, d);
      if (lane >= d) v += t;
    }
    if (lane == 63) wsum[w] = v;
    __syncthreads();
    if (w == 0) {
      int x = (lane < 16) ? wsum[lane] : 0;
      #pragma unroll
      for (int d = 1; d < 16; d <<= 1) {
        int t = __shfl_up(x, d);
        if (lane >= d) x += t;
      }
      if (lane < 16) wsum[lane] = x;
    }
    __syncthreads();
    int waveoff = (w == 0) ? 0 : wsum[w - 1];
    int total = wsum[15];
    if (i < n) row_ptr[i + 1] = base_s + waveoff + v;
    __syncthreads();
    if (tid == 0) base_s += total;
    __syncthreads();
  }
}

__global__ void scatter_kernel(const void* ei, const int* __restrict__ flag,
                               const int* __restrict__ row_ptr, int* __restrict__ cur,
                               int2* __restrict__ ec, int E) {
  int e = blockIdx.x * blockDim.x + threadIdx.x;
  if (e >= E) return;
  int f = flag[0];
  int r = load_idx(ei, e, f);
  int c = load_idx(ei, (long long)E + e, f);
  int pos = row_ptr[r] + atomicAdd(&cur[r], 1);
  ec[pos] = make_int2(e, c);
}

// --- sg = h @ [W1top|W1mid] (+b1 on first 128 cols); block=256 (4 waves x 16 rows) ---
__global__ __launch_bounds__(256) void sg_kernel(const float* __restrict__ h,
                                                 const short* __restrict__ w12t,
                                                 const float* __restrict__ b1,
                                                 float* __restrict__ sg, int N) {
  int lane = threadIdx.x & 63, w = threadIdx.x >> 6;
  int li = lane & 15, lg = lane >> 4;
  int base = blockIdx.x * 64 + w * 16;
  int rowm = base + li;
  if (rowm >= N) rowm = N - 1;
  float breg[8];
  #pragma unroll
  for (int nt = 0; nt < 8; ++nt) breg[nt] = b1[nt * 16 + li];
  f32x4 acc[16];
  #pragma unroll
  for (int nt = 0; nt < 16; ++nt) acc[nt] = (f32x4){0.f, 0.f, 0.f, 0.f};
  #pragma unroll
  for (int kc = 0; kc < 4; ++kc) {
    f32x4 f0 = *(const f32x4*)(h + rowm * ND + kc * 32 + lg * 8);
    f32x4 f1 = *(const f32x4*)(h + rowm * ND + kc * 32 + lg * 8 + 4);
    bf16x8 a;
    #pragma unroll
    for (int j = 0; j < 4; ++j) { a[j] = f2bf(f0[j]); a[4 + j] = f2bf(f1[j]); }
    #pragma unroll
    for (int nt = 0; nt < 16; ++nt) {
      bf16x8 b = *(const bf16x8*)(w12t + (nt * 16 + li) * 128 + kc * 32 + lg * 8);
      acc[nt] = __builtin_amdgcn_mfma_f32_16x16x32_bf16(a, b, acc[nt], 0, 0, 0);
    }
  }
  #pragma unroll
  for (int nt = 0; nt < 16; ++nt)
    #pragma unroll
    for (int r = 0; r < 4; ++r) {
      int row = base + lg * 4 + r;
      if (row < N) {
        float bias = (nt < 8) ? breg[nt] : 0.f;
        sg[row * 256 + nt * 16 + li] = acc[nt][r] + bias;
      }
    }
}

// --- layer 1 + segment reduce: 2 waves per node (col halves), K=32 MFMA, edge-per-lane ---
__global__ __launch_bounds__(128, 4) void layer1_kernel(
    const float* __restrict__ sg, const float* __restrict__ ef,
    const short* __restrict__ w1eA, const int2* __restrict__ ec,
    const int* __restrict__ row_ptr, float* __restrict__ hsum) {
  int node = blockIdx.x;
  int lane = threadIdx.x & 63;
  int w = threadIdx.x >> 6;           // col-half: 0 or 1
  int li = lane & 15, lg = lane >> 4;
  int rp = row_ptr[node], rpe = row_ptr[node + 1];
  int deg = rpe - rp;
  int cb = w * 64;                    // this wave's column base

  if (deg == 0) {
    if (li == 0) {
      #pragma unroll
      for (int nt = 0; nt < 4; ++nt)
        *(f32x4*)(hsum + node * 128 + cb + nt * 16 + lg * 4) = (f32x4){0.f, 0.f, 0.f, 0.f};
    }
    return;
  }

  // W1e A-frags for this wave's 4 output-col tiles
  bf16x8 wa[4];
  #pragma unroll
  for (int nt = 0; nt < 4; ++nt)
    wa[nt] = *(const bf16x8*)(w1eA + ((w * 4 + nt) * 64 + lane) * 8);
  // s (same for all edges of this node)
  f32x4 sreg[4];
  #pragma unroll
  for (int nt = 0; nt < 4; ++nt)
    sreg[nt] = *(const f32x4*)(sg + (size_t)node * 256 + cb + nt * 16 + lg * 4);

  f32x4 psum[4];
  #pragma unroll
  for (int nt = 0; nt < 4; ++nt) psum[nt] = (f32x4){0.f, 0.f, 0.f, 0.f};

  int ntiles = (deg + 15) >> 4;
  int last = rpe - 1;
  auto ldidx = [&](int t) {
    int p = rp + t * 16 + li;
    return ec[p > last ? last : p];
  };

  int2 iA = ldidx(0);
  int2 iB = ldidx(1);
  f32x4 e0 = *(const f32x4*)(ef + (size_t)iA.x * ED + lg * 8);
  f32x4 e1 = *(const f32x4*)(ef + (size_t)iA.x * ED + lg * 8 + 4);

  for (int t = 0; t < ntiles; ++t) {
    int2 iC = ldidx(t + 2);
    // gather g[col] for current tile's edge (one edge per li-lane)
    const float* gp = sg + (size_t)iA.y * 256 + 128 + cb;
    f32x4 gv[4];
    #pragma unroll
    for (int nt = 0; nt < 4; ++nt) gv[nt] = *(const f32x4*)(gp + nt * 16 + lg * 4);
    // B-frag from ef (B[k][edge]: lane holds ef[own edge][lg*8+j])
    bf16x8 bf;
    #pragma unroll
    for (int j = 0; j < 4; ++j) { bf[j] = f2bf(e0[j]); bf[4 + j] = f2bf(e1[j]); }
    // t-tile: D[outcol][edge]
    f32x4 acc[4];
    #pragma unroll
    for (int nt = 0; nt < 4; ++nt)
      acc[nt] = __builtin_amdgcn_mfma_f32_16x16x32_bf16(wa[nt], bf, (f32x4){0.f, 0.f, 0.f, 0.f}, 0, 0, 0);
    // prefetch next tile's ef
    f32x4 e0n = *(const f32x4*)(ef + (size_t)iB.x * ED + lg * 8);
    f32x4 e1n = *(const f32x4*)(ef + (size_t)iB.x * ED + lg * 8 + 4);
    // combine + accumulate (lane owns edge li of this tile, cols cb+nt*16+lg*4..+3)
    bool valid = (t * 16 + li) < deg;
    if (valid) {
      #pragma unroll
      for (int nt = 0; nt < 4; ++nt) {
        f32x4 v = acc[nt] + sreg[nt] + gv[nt];
        #pragma unroll
        for (int r = 0; r < 4; ++r) {
          float x = v[r];
          psum[nt][r] += (x > 0.f ? x : 0.f);
        }
      }
    }
    iA = iB; iB = iC; e0 = e0n; e1 = e1n;
  }

  // reduce across the 16 li-lanes (edges), then store from li==0
  #pragma unroll
  for (int nt = 0; nt < 4; ++nt)
    #pragma unroll
    for (int r = 0; r < 4; ++r) {
      float v = psum[nt][r];
      v += __shfl_xor(v, 1);
      v += __shfl_xor(v, 2);
      v += __shfl_xor(v, 4);
      v += __shfl_xor(v, 8);
      psum[nt][r] = v;
    }
  if (li == 0) {
    #pragma unroll
    for (int nt = 0; nt < 4; ++nt)
      *(f32x4*)(hsum + (size_t)node * 128 + cb + nt * 16 + lg * 4) = psum[nt];
  }
}

// --- out = Hsum @ W2 + deg*b2 ---
__global__ __launch_bounds__(64) void out_kernel(const float* __restrict__ hsum,
                                                 const short* __restrict__ w2t,
                                                 const float* __restrict__ b2,
                                                 const int* __restrict__ row_ptr,
                                                 float* __restrict__ out, int N) {
  int lane = threadIdx.x, li = lane & 15, lg = lane >> 4;
  int base = blockIdx.x * 64;
  float breg[8];
  #pragma unroll
  for (int nt = 0; nt < 8; ++nt) breg[nt] = b2[nt * 16 + li];
  f32x4 acc[4][8];
  #pragma unroll
  for (int m = 0; m < 4; ++m)
    #pragma unroll
    for (int nt = 0; nt < 8; ++nt) acc[m][nt] = (f32x4){0.f, 0.f, 0.f, 0.f};
  int rowm[4];
  #pragma unroll
  for (int m = 0; m < 4; ++m) {
    int r = base + m * 16 + li;
    rowm[m] = r < N ? r : N - 1;
  }
  #pragma unroll
  for (int kc = 0; kc < 4; ++kc) {
    bf16x8 a[4];
    #pragma unroll
    for (int m = 0; m < 4; ++m) {
      f32x4 f0 = *(const f32x4*)(hsum + rowm[m] * 128 + kc * 32 + lg * 8);
      f32x4 f1 = *(const f32x4*)(hsum + rowm[m] * 128 + kc * 32 + lg * 8 + 4);
      bf16x8 tt;
      #pragma unroll
      for (int j = 0; j < 4; ++j) { tt[j] = f2bf(f0[j]); tt[4 + j] = f2bf(f1[j]); }
      a[m] = tt;
    }
    #pragma unroll
    for (int nt = 0; nt < 8; ++nt) {
      bf16x8 b = *(const bf16x8*)(w2t + (nt * 16 + li) * 128 + kc * 32 + lg * 8);
      #pragma unroll
      for (int m = 0; m < 4; ++m)
        acc[m][nt] = __builtin_amdgcn_mfma_f32_16x16x32_bf16(a[m], b, acc[m][nt], 0, 0, 0);
    }
  }
  #pragma unroll
  for (int m = 0; m < 4; ++m)
    #pragma unroll
    for (int r = 0; r < 4; ++r) {
      int row = base + m * 16 + lg * 4 + r;
      if (row < N) {
        int dg = row_ptr[row + 1] - row_ptr[row];
        #pragma unroll
        for (int nt = 0; nt < 8; ++nt)
          out[row * 128 + nt * 16 + li] = acc[m][nt][r] + (float)dg * breg[nt];
      }
    }
}

extern "C" void kernel_launch(void* const* d_in, const int* in_sizes, int n_in,
                              void* d_out, int out_size, void* d_ws, size_t ws_size,
                              hipStream_t stream) {
  const float* h  = (const float*)d_in[0];
  const void*  ei = d_in[1];
  const float* ef = (const float*)d_in[2];
  const float* W1 = (const float*)d_in[4];
  const float* b1 = (const float*)d_in[5];
  const float* W2 = (const float*)d_in[6];
  const float* b2 = (const float*)d_in[7];
  float* out = (float*)d_out;
  int N = in_sizes[0] / ND;
  int E = in_sizes[2] / ED;

  char* ws = (char*)d_ws;
  size_t off = 0;
  auto alloc = [&](size_t bytes) {
    size_t o = off;
    off = (off + bytes + 255) & ~(size_t)255;
    return o;
  };
  int*   flag    = (int*)(ws + alloc(4));
  int*   counts  = (int*)(ws + alloc((size_t)N * 4));
  int*   cur     = (int*)(ws + alloc((size_t)N * 4));
  int*   row_ptr = (int*)(ws + alloc((size_t)(N + 1) * 4));
  int2*  ec      = (int2*)(ws + alloc((size_t)E * 8));
  short* w12t    = (short*)(ws + alloc(256 * 128 * 2));
  short* w1eA    = (short*)(ws + alloc(8 * 64 * 8 * 2));
  short* w2t     = (short*)(ws + alloc(128 * 128 * 2));
  float* sgbuf   = (float*)(ws + alloc((size_t)N * 256 * 4));
  float* hsumb   = (float*)(ws + alloc((size_t)N * 128 * 4));

  hipMemsetAsync(counts, 0, (size_t)N * 4, stream);
  hipMemsetAsync(cur, 0, (size_t)N * 4, stream);
  detect_kernel<<<1, 64, 0, stream>>>((const unsigned int*)ei, flag);
  prep_kernel<<<128, 256, 0, stream>>>(W1, W2, w12t, w1eA, w2t);
  hist_kernel<<<(E + 255) / 256, 256, 0, stream>>>(ei, flag, counts, E);
  scan_kernel<<<1, 1024, 0, stream>>>(counts, row_ptr, N);
  scatter_kernel<<<(E + 255) / 256, 256, 0, stream>>>(ei, flag, row_ptr, cur, ec, E);
  sg_kernel<<<(N + 63) / 64, 256, 0, stream>>>(h, w12t, b1, sgbuf, N);
  layer1_kernel<<<N, 128, 0, stream>>>(sgbuf, ef, w1eA, ec, row_ptr, hsumb);
  out_kernel<<<(N + 63) / 64, 64, 0, stream>>>(hsumb, w2t, b2, row_ptr, out, N);
}

// Round 3
// 190.158 us; speedup vs baseline: 1.3447x; 1.0746x over previous
//
#include <hip/hip_runtime.h>
#include <hip/hip_bf16.h>

// MPNNConv restructured:
//   s[n] = h[n] @ W1[0:128] + b1 (f32), g[n] = h[n] @ W1[128:256] (bf16, L2-resident 2.5MB)
//   Hsum[n] = sum_{e: rows[e]=n} relu(s[n] + g[cols[e]] + ef[e] @ W1e)   (K=32 MFMA)
//   out[n]  = Hsum[n] @ W2 + deg[n]*b2
// CSR built on-device: hist(rank via atomic) -> scan -> scatter (atomic-free).
// layer1: 4 waves/node (32 cols each), edge-per-lane tiles of 16,
//         ef + g gathers software-pipelined one tile ahead.

typedef __attribute__((ext_vector_type(8))) short bf16x8;
typedef __attribute__((ext_vector_type(4))) short s16x4;
typedef __attribute__((ext_vector_type(4))) float f32x4;

#define ND 128
#define ED 32

__device__ __forceinline__ short f2bf(float x) {
  unsigned int u = __float_as_uint(x);
  unsigned int r = (u + 0x7FFFu + ((u >> 16) & 1u)) >> 16;
  return (short)r;
}

__device__ __forceinline__ f32x4 bf4_to_f32(s16x4 v) {
  f32x4 r;
  #pragma unroll
  for (int j = 0; j < 4; ++j)
    r[j] = __uint_as_float(((unsigned int)(unsigned short)v[j]) << 16);
  return r;
}

__device__ __forceinline__ int load_idx(const void* ei, long long i, int is64) {
  return is64 ? (int)((const long long*)ei)[i] : ((const int*)ei)[i];
}

// --- weight pre-layouts + int64/int32 detect (fused) ---
__global__ void prep_kernel(const float* __restrict__ W1, const float* __restrict__ W2,
                            const unsigned int* __restrict__ ei,
                            short* __restrict__ w12t, short* __restrict__ w1eA,
                            short* __restrict__ w2t, int* __restrict__ flag) {
  if (blockIdx.x == 0 && threadIdx.x == 0) {
    int is64 = 1;
    for (int i = 0; i < 16; ++i)
      if (ei[2 * i + 1] != 0u) is64 = 0;
    flag[0] = is64;
  }
  int t = blockIdx.x * blockDim.x + threadIdx.x;
  if (t < 256 * 128) {  // w12t[n'][k]: n'<128 -> W1[k][n'] ; n'>=128 -> W1[128+k][n'-128]
    int np = t >> 7, k = t & 127;
    float v = (np < 128) ? W1[k * 128 + np] : W1[(128 + k) * 128 + (np - 128)];
    w12t[t] = f2bf(v);
  }
  if (t < 128 * 128) {  // w2t[n][k] = W2[k][n]
    int n = t >> 7, k = t & 127;
    w2t[t] = f2bf(W2[k * 128 + n]);
  }
  if (t < 8 * 64 * 8) { // w1eA[nt][lane][j] = W1[256 + lg*8+j][nt*16+li]  (A-frag of W1e^T)
    int nt = t >> 9, lane = (t >> 3) & 63, j = t & 7;
    int li = lane & 15, lg = lane >> 4;
    w1eA[t] = f2bf(W1[(256 + lg * 8 + j) * 128 + nt * 16 + li]);
  }
}

// --- histogram + per-edge rank (one atomic per edge total for CSR build) ---
__global__ void hist_kernel(const void* ei, const int* __restrict__ flag,
                            int* __restrict__ counts, int* __restrict__ rank, int E) {
  int e = blockIdx.x * blockDim.x + threadIdx.x;
  if (e >= E) return;
  int r = load_idx(ei, e, flag[0]);
  rank[e] = atomicAdd(&counts[r], 1);
}

// single-block exclusive scan of counts[0..n) -> row_ptr[0..n]
__global__ void scan_kernel(const int* __restrict__ counts, int* __restrict__ row_ptr, int n) {
  __shared__ int wsum[16];
  __shared__ int base_s;
  int tid = threadIdx.x;
  int lane = tid & 63, w = tid >> 6;
  if (tid == 0) { base_s = 0; row_ptr[0] = 0; }
  __syncthreads();
  for (int start = 0; start < n; start += 1024) {
    int i = start + tid;
    int v = (i < n) ? counts[i] : 0;
    #pragma unroll
    for (int d = 1; d < 64; d <<= 1) {
      int t = __shfl_up(v, d);
      if (lane >= d) v += t;
    }
    if (lane == 63) wsum[w] = v;
    __syncthreads();
    if (w == 0) {
      int x = (lane < 16) ? wsum[lane] : 0;
      #pragma unroll
      for (int d = 1; d < 16; d <<= 1) {
        int t = __shfl_up(x, d);
        if (lane >= d) x += t;
      }
      if (lane < 16) wsum[lane] = x;
    }
    __syncthreads();
    int waveoff = (w == 0) ? 0 : wsum[w - 1];
    int total = wsum[15];
    if (i < n) row_ptr[i + 1] = base_s + waveoff + v;
    __syncthreads();
    if (tid == 0) base_s += total;
    __syncthreads();
  }
}

// --- atomic-free scatter using precomputed rank ---
__global__ void scatter_kernel(const void* ei, const int* __restrict__ flag,
                               const int* __restrict__ row_ptr, const int* __restrict__ rank,
                               int2* __restrict__ ec, int E) {
  int e = blockIdx.x * blockDim.x + threadIdx.x;
  if (e >= E) return;
  int f = flag[0];
  int r = load_idx(ei, e, f);
  int c = load_idx(ei, (long long)E + e, f);
  ec[row_ptr[r] + rank[e]] = make_int2(e, c);
}

// --- s = h@W1top + b1 (f32), g = h@W1mid (bf16); block=256 (4 waves x 16 rows) ---
__global__ __launch_bounds__(256) void sg_kernel(const float* __restrict__ h,
                                                 const short* __restrict__ w12t,
                                                 const float* __restrict__ b1,
                                                 float* __restrict__ s,
                                                 short* __restrict__ gb, int N) {
  int lane = threadIdx.x & 63, w = threadIdx.x >> 6;
  int li = lane & 15, lg = lane >> 4;
  int base = blockIdx.x * 64 + w * 16;
  int rowm = base + li;
  if (rowm >= N) rowm = N - 1;
  float breg[8];
  #pragma unroll
  for (int nt = 0; nt < 8; ++nt) breg[nt] = b1[nt * 16 + li];
  f32x4 acc[16];
  #pragma unroll
  for (int nt = 0; nt < 16; ++nt) acc[nt] = (f32x4){0.f, 0.f, 0.f, 0.f};
  #pragma unroll
  for (int kc = 0; kc < 4; ++kc) {
    f32x4 f0 = *(const f32x4*)(h + rowm * ND + kc * 32 + lg * 8);
    f32x4 f1 = *(const f32x4*)(h + rowm * ND + kc * 32 + lg * 8 + 4);
    bf16x8 a;
    #pragma unroll
    for (int j = 0; j < 4; ++j) { a[j] = f2bf(f0[j]); a[4 + j] = f2bf(f1[j]); }
    #pragma unroll
    for (int nt = 0; nt < 16; ++nt) {
      bf16x8 b = *(const bf16x8*)(w12t + (nt * 16 + li) * 128 + kc * 32 + lg * 8);
      acc[nt] = __builtin_amdgcn_mfma_f32_16x16x32_bf16(a, b, acc[nt], 0, 0, 0);
    }
  }
  #pragma unroll
  for (int nt = 0; nt < 16; ++nt)
    #pragma unroll
    for (int r = 0; r < 4; ++r) {
      int row = base + lg * 4 + r;
      if (row < N) {
        if (nt < 8)
          s[row * 128 + nt * 16 + li] = acc[nt][r] + breg[nt];
        else
          gb[row * 128 + (nt - 8) * 16 + li] = f2bf(acc[nt][r]);
      }
    }
}

// --- layer 1 + segment reduce: 4 waves/node (32 cols each), pipelined gathers ---
__global__ __launch_bounds__(256, 6) void layer1_kernel(
    const float* __restrict__ s, const short* __restrict__ gb,
    const float* __restrict__ ef, const short* __restrict__ w1eA,
    const int2* __restrict__ ec, const int* __restrict__ row_ptr,
    float* __restrict__ hsum) {
  int node = blockIdx.x;
  int lane = threadIdx.x & 63;
  int w = threadIdx.x >> 6;           // col quarter: 0..3
  int li = lane & 15, lg = lane >> 4;
  int rp = row_ptr[node], rpe = row_ptr[node + 1];
  int deg = rpe - rp;
  int cb = w * 32;                    // this wave's column base

  if (deg == 0) {
    if (li == 0) {
      #pragma unroll
      for (int nt = 0; nt < 2; ++nt)
        *(f32x4*)(hsum + (size_t)node * 128 + cb + nt * 16 + lg * 4) = (f32x4){0.f, 0.f, 0.f, 0.f};
    }
    return;
  }

  bf16x8 wa[2];
  #pragma unroll
  for (int nt = 0; nt < 2; ++nt)
    wa[nt] = *(const bf16x8*)(w1eA + ((w * 2 + nt) * 64 + lane) * 8);
  f32x4 sreg[2];
  #pragma unroll
  for (int nt = 0; nt < 2; ++nt)
    sreg[nt] = *(const f32x4*)(s + (size_t)node * 128 + cb + nt * 16 + lg * 4);

  f32x4 psum[2];
  #pragma unroll
  for (int nt = 0; nt < 2; ++nt) psum[nt] = (f32x4){0.f, 0.f, 0.f, 0.f};

  int ntiles = (deg + 15) >> 4;
  int last = rpe - 1;
  auto ldidx = [&](int t) {
    int p = rp + t * 16 + li;
    return ec[p > last ? last : p];
  };

  int2 iA = ldidx(0);
  int2 iB = ldidx(1);
  // prefetch tile 0 payloads
  const float* efA = ef + (size_t)iA.x * ED;
  f32x4 e0 = *(const f32x4*)(efA + lg * 8);
  f32x4 e1 = *(const f32x4*)(efA + lg * 8 + 4);
  const short* gpA = gb + (size_t)iA.y * 128 + cb;
  s16x4 gA0 = *(const s16x4*)(gpA + lg * 4);
  s16x4 gA1 = *(const s16x4*)(gpA + 16 + lg * 4);

  for (int t = 0; t < ntiles; ++t) {
    int2 iC = ldidx(t + 2);
    // issue next tile's loads early (hide under this tile's compute)
    const float* efB = ef + (size_t)iB.x * ED;
    f32x4 e0n = *(const f32x4*)(efB + lg * 8);
    f32x4 e1n = *(const f32x4*)(efB + lg * 8 + 4);
    const short* gpB = gb + (size_t)iB.y * 128 + cb;
    s16x4 gB0 = *(const s16x4*)(gpB + lg * 4);
    s16x4 gB1 = *(const s16x4*)(gpB + 16 + lg * 4);
    // compute current tile
    bf16x8 bf;
    #pragma unroll
    for (int j = 0; j < 4; ++j) { bf[j] = f2bf(e0[j]); bf[4 + j] = f2bf(e1[j]); }
    f32x4 acc0 = __builtin_amdgcn_mfma_f32_16x16x32_bf16(wa[0], bf, (f32x4){0.f, 0.f, 0.f, 0.f}, 0, 0, 0);
    f32x4 acc1 = __builtin_amdgcn_mfma_f32_16x16x32_bf16(wa[1], bf, (f32x4){0.f, 0.f, 0.f, 0.f}, 0, 0, 0);
    if ((t * 16 + li) < deg) {
      f32x4 v0 = acc0 + sreg[0] + bf4_to_f32(gA0);
      f32x4 v1 = acc1 + sreg[1] + bf4_to_f32(gA1);
      #pragma unroll
      for (int r = 0; r < 4; ++r) {
        psum[0][r] += (v0[r] > 0.f ? v0[r] : 0.f);
        psum[1][r] += (v1[r] > 0.f ? v1[r] : 0.f);
      }
    }
    iA = iB; iB = iC;
    e0 = e0n; e1 = e1n; gA0 = gB0; gA1 = gB1;
  }

  // reduce across the 16 li-lanes (edges), store from li==0
  #pragma unroll
  for (int nt = 0; nt < 2; ++nt)
    #pragma unroll
    for (int r = 0; r < 4; ++r) {
      float v = psum[nt][r];
      v += __shfl_xor(v, 1);
      v += __shfl_xor(v, 2);
      v += __shfl_xor(v, 4);
      v += __shfl_xor(v, 8);
      psum[nt][r] = v;
    }
  if (li == 0) {
    #pragma unroll
    for (int nt = 0; nt < 2; ++nt)
      *(f32x4*)(hsum + (size_t)node * 128 + cb + nt * 16 + lg * 4) = psum[nt];
  }
}

// --- out = Hsum @ W2 + deg*b2 ---
__global__ __launch_bounds__(64) void out_kernel(const float* __restrict__ hsum,
                                                 const short* __restrict__ w2t,
                                                 const float* __restrict__ b2,
                                                 const int* __restrict__ row_ptr,
                                                 float* __restrict__ out, int N) {
  int lane = threadIdx.x, li = lane & 15, lg = lane >> 4;
  int base = blockIdx.x * 64;
  float breg[8];
  #pragma unroll
  for (int nt = 0; nt < 8; ++nt) breg[nt] = b2[nt * 16 + li];
  f32x4 acc[4][8];
  #pragma unroll
  for (int m = 0; m < 4; ++m)
    #pragma unroll
    for (int nt = 0; nt < 8; ++nt) acc[m][nt] = (f32x4){0.f, 0.f, 0.f, 0.f};
  int rowm[4];
  #pragma unroll
  for (int m = 0; m < 4; ++m) {
    int r = base + m * 16 + li;
    rowm[m] = r < N ? r : N - 1;
  }
  #pragma unroll
  for (int kc = 0; kc < 4; ++kc) {
    bf16x8 a[4];
    #pragma unroll
    for (int m = 0; m < 4; ++m) {
      f32x4 f0 = *(const f32x4*)(hsum + rowm[m] * 128 + kc * 32 + lg * 8);
      f32x4 f1 = *(const f32x4*)(hsum + rowm[m] * 128 + kc * 32 + lg * 8 + 4);
      bf16x8 tt;
      #pragma unroll
      for (int j = 0; j < 4; ++j) { tt[j] = f2bf(f0[j]); tt[4 + j] = f2bf(f1[j]); }
      a[m] = tt;
    }
    #pragma unroll
    for (int nt = 0; nt < 8; ++nt) {
      bf16x8 b = *(const bf16x8*)(w2t + (nt * 16 + li) * 128 + kc * 32 + lg * 8);
      #pragma unroll
      for (int m = 0; m < 4; ++m)
        acc[m][nt] = __builtin_amdgcn_mfma_f32_16x16x32_bf16(a[m], b, acc[m][nt], 0, 0, 0);
    }
  }
  #pragma unroll
  for (int m = 0; m < 4; ++m)
    #pragma unroll
    for (int r = 0; r < 4; ++r) {
      int row = base + m * 16 + lg * 4 + r;
      if (row < N) {
        int dg = row_ptr[row + 1] - row_ptr[row];
        #pragma unroll
        for (int nt = 0; nt < 8; ++nt)
          out[row * 128 + nt * 16 + li] = acc[m][nt][r] + (float)dg * breg[nt];
      }
    }
}

extern "C" void kernel_launch(void* const* d_in, const int* in_sizes, int n_in,
                              void* d_out, int out_size, void* d_ws, size_t ws_size,
                              hipStream_t stream) {
  const float* h  = (const float*)d_in[0];
  const void*  ei = d_in[1];
  const float* ef = (const float*)d_in[2];
  const float* W1 = (const float*)d_in[4];
  const float* b1 = (const float*)d_in[5];
  const float* W2 = (const float*)d_in[6];
  const float* b2 = (const float*)d_in[7];
  float* out = (float*)d_out;
  int N = in_sizes[0] / ND;
  int E = in_sizes[2] / ED;

  char* ws = (char*)d_ws;
  size_t off = 0;
  auto alloc = [&](size_t bytes) {
    size_t o = off;
    off = (off + bytes + 255) & ~(size_t)255;
    return o;
  };
  int*   flag    = (int*)(ws + alloc(4));
  int*   counts  = (int*)(ws + alloc((size_t)N * 4));
  int*   row_ptr = (int*)(ws + alloc((size_t)(N + 1) * 4));
  int*   rank    = (int*)(ws + alloc((size_t)E * 4));
  int2*  ec      = (int2*)(ws + alloc((size_t)E * 8));
  short* w12t    = (short*)(ws + alloc(256 * 128 * 2));
  short* w1eA    = (short*)(ws + alloc(8 * 64 * 8 * 2));
  short* w2t     = (short*)(ws + alloc(128 * 128 * 2));
  float* sbuf    = (float*)(ws + alloc((size_t)N * 128 * 4));
  short* gbuf    = (short*)(ws + alloc((size_t)N * 128 * 2));
  float* hsumb   = (float*)(ws + alloc((size_t)N * 128 * 4));

  hipMemsetAsync(counts, 0, (size_t)N * 4, stream);
  prep_kernel<<<128, 256, 0, stream>>>(W1, W2, (const unsigned int*)ei, w12t, w1eA, w2t, flag);
  hist_kernel<<<(E + 255) / 256, 256, 0, stream>>>(ei, flag, counts, rank, E);
  scan_kernel<<<1, 1024, 0, stream>>>(counts, row_ptr, N);
  scatter_kernel<<<(E + 255) / 256, 256, 0, stream>>>(ei, flag, row_ptr, rank, ec, E);
  sg_kernel<<<(N + 63) / 64, 256, 0, stream>>>(h, w12t, b1, sbuf, gbuf, N);
  layer1_kernel<<<N, 256, 0, stream>>>(sbuf, gbuf, ef, w1eA, ec, row_ptr, hsumb);
  out_kernel<<<(N + 63) / 64, 64, 0, stream>>>(hsumb, w2t, b2, row_ptr, out, N);
}

// Round 4
// 134.549 us; speedup vs baseline: 1.9005x; 1.4133x over previous
//
#include <hip/hip_runtime.h>
#include <hip/hip_bf16.h>

// MPNNConv restructured:
//   s[n] = h[n] @ W1[0:128] + b1, g[n] = h[n] @ W1[128:256] (bf16, L2-resident)
//   Hsum[n] = sum_{e: rows[e]=n} relu(s[n] + g[cols[e]] + ef[e] @ W1e)   (K=32 MFMA)
//   out[n]  = Hsum[n] @ W2 + deg[n]*b2
// CSR on-device; ef permuted into CSR order as bf16 (efb) so layer1 streams
// its edge payload coalesced. g/s stored in lane-contiguous swizzled layout.

typedef __attribute__((ext_vector_type(8))) short bf16x8;
typedef __attribute__((ext_vector_type(4))) short s16x4;
typedef __attribute__((ext_vector_type(4))) float f32x4;

#define ND 128
#define ED 32

__device__ __forceinline__ short f2bf(float x) {
  unsigned int u = __float_as_uint(x);
  unsigned int r = (u + 0x7FFFu + ((u >> 16) & 1u)) >> 16;
  return (short)r;
}

__device__ __forceinline__ float bf2f(short s) {
  return __uint_as_float(((unsigned int)(unsigned short)s) << 16);
}

// lo half (elems 0..3) / hi half (elems 4..7) of a bf16x8 -> f32x4
__device__ __forceinline__ f32x4 bf8lo(bf16x8 v) {
  f32x4 r;
  #pragma unroll
  for (int j = 0; j < 4; ++j) r[j] = bf2f(v[j]);
  return r;
}
__device__ __forceinline__ f32x4 bf8hi(bf16x8 v) {
  f32x4 r;
  #pragma unroll
  for (int j = 0; j < 4; ++j) r[j] = bf2f(v[4 + j]);
  return r;
}

__device__ __forceinline__ int load_idx(const void* ei, long long i, int is64) {
  return is64 ? (int)((const long long*)ei)[i] : ((const int*)ei)[i];
}

__device__ __forceinline__ int detect64(const void* ei) {
  const unsigned int* u = (const unsigned int*)ei;
  int is64 = 1;
  #pragma unroll
  for (int i = 0; i < 16; ++i)
    if (u[2 * i + 1] != 0u) is64 = 0;
  return is64;
}

// swizzled offset within a 128-wide row for col c:
// o = (ct>>2)*64 + (li>>2)*16 + (ct&3)*4 + (li&3),  ct=c>>4, li=c&15
__device__ __forceinline__ int swz(int c) {
  int ct = c >> 4, li = c & 15;
  return (ct >> 2) * 64 + (li >> 2) * 16 + (ct & 3) * 4 + (li & 3);
}

// --- fused: weight pre-layouts (blocks [0,128)) + histogram/rank (rest) ---
__global__ __launch_bounds__(256) void prep_hist_kernel(
    const float* __restrict__ W1, const float* __restrict__ W2,
    const void* __restrict__ ei, int* __restrict__ counts,
    int* __restrict__ rank, short* __restrict__ w12t,
    short* __restrict__ w1eA, short* __restrict__ w2t, int E) {
  int b = blockIdx.x;
  if (b < 128) {
    int t = b * 256 + threadIdx.x;
    if (t < 256 * 128) {  // w12t[n'][k]: n'<128 -> W1[k][n'] ; else W1[128+k][n'-128]
      int np = t >> 7, k = t & 127;
      float v = (np < 128) ? W1[k * 128 + np] : W1[(128 + k) * 128 + (np - 128)];
      w12t[t] = f2bf(v);
    }
    if (t < 128 * 128) {
      int n = t >> 7, k = t & 127;
      w2t[t] = f2bf(W2[k * 128 + n]);
    }
    if (t < 8 * 64 * 8) {  // w1eA[ct][lane][j] = W1[256+lg*8+j][ct*16+li]
      int ct = t >> 9, lane = (t >> 3) & 63, j = t & 7;
      int li = lane & 15, lg = lane >> 4;
      w1eA[t] = f2bf(W1[(256 + lg * 8 + j) * 128 + ct * 16 + li]);
    }
  } else {
    int e = (b - 128) * 256 + threadIdx.x;
    if (e < E) {
      int is64 = detect64(ei);
      int r = load_idx(ei, e, is64);
      rank[e] = atomicAdd(&counts[r], 1);
    }
  }
}

// --- single-block scan: 1024 threads x 16 elems ---
__global__ __launch_bounds__(1024) void scan_kernel(const int* __restrict__ counts,
                                                    int* __restrict__ row_ptr, int n) {
  __shared__ int wtot[16];
  int tid = threadIdx.x;
  int lane = tid & 63, w = tid >> 6;
  int base_i = tid * 16;
  int c[16];
  int tot = 0;
  #pragma unroll
  for (int j = 0; j < 16; ++j) {
    int i = base_i + j;
    c[j] = (i < n) ? counts[i] : 0;
    tot += c[j];
  }
  int x = tot;
  #pragma unroll
  for (int d = 1; d < 64; d <<= 1) {
    int t = __shfl_up(x, d);
    if (lane >= d) x += t;
  }
  if (lane == 63) wtot[w] = x;
  __syncthreads();
  if (w == 0) {
    int y = (lane < 16) ? wtot[lane] : 0;
    #pragma unroll
    for (int d = 1; d < 16; d <<= 1) {
      int t = __shfl_up(y, d);
      if (lane >= d) y += t;
    }
    if (lane < 16) wtot[lane] = y;
  }
  __syncthreads();
  int waveoff = (w == 0) ? 0 : wtot[w - 1];
  int run = waveoff + x - tot;  // exclusive prefix
  if (tid == 0) row_ptr[0] = 0;
  #pragma unroll
  for (int j = 0; j < 16; ++j) {
    int i = base_i + j;
    if (i < n) {
      run += c[j];
      row_ptr[i + 1] = run;
    }
  }
}

// --- fused: sg GEMM (blocks [0,SGB)) + scatter/ef-permute (rest) ---
template <int MODE>  // 0: permute ef->efb(bf16)+ccol ; 1: write ec pairs only
__global__ __launch_bounds__(256, 4) void scatter_sg_kernel(
    const void* __restrict__ ei, const float* __restrict__ ef,
    const int* __restrict__ row_ptr, const int* __restrict__ rank,
    const float* __restrict__ h, const short* __restrict__ w12t,
    const float* __restrict__ b1, short* __restrict__ efb,
    int* __restrict__ ccol, int2* __restrict__ ec,
    float* __restrict__ s2, short* __restrict__ g2, int N, int E) {
  int b = blockIdx.x;
  int SGB = (N + 63) >> 6;
  if (b < SGB) {
    // ---- sg: s = h@W1top + b1 (f32, swizzled), g = h@W1mid (bf16, swizzled)
    int lane = threadIdx.x & 63, w = threadIdx.x >> 6;
    int li = lane & 15, lg = lane >> 4;
    int base = b * 64 + w * 16;
    int rowm = base + li;
    if (rowm >= N) rowm = N - 1;
    float breg[8];
    #pragma unroll
    for (int nt = 0; nt < 8; ++nt) breg[nt] = b1[nt * 16 + li];
    f32x4 acc[16];
    #pragma unroll
    for (int nt = 0; nt < 16; ++nt) acc[nt] = (f32x4){0.f, 0.f, 0.f, 0.f};
    #pragma unroll
    for (int kc = 0; kc < 4; ++kc) {
      f32x4 f0 = *(const f32x4*)(h + (size_t)rowm * ND + kc * 32 + lg * 8);
      f32x4 f1 = *(const f32x4*)(h + (size_t)rowm * ND + kc * 32 + lg * 8 + 4);
      bf16x8 a;
      #pragma unroll
      for (int j = 0; j < 4; ++j) { a[j] = f2bf(f0[j]); a[4 + j] = f2bf(f1[j]); }
      #pragma unroll
      for (int nt = 0; nt < 16; ++nt) {
        bf16x8 bb = *(const bf16x8*)(w12t + (nt * 16 + li) * 128 + kc * 32 + lg * 8);
        acc[nt] = __builtin_amdgcn_mfma_f32_16x16x32_bf16(a, bb, acc[nt], 0, 0, 0);
      }
    }
    #pragma unroll
    for (int nt = 0; nt < 16; ++nt)
      #pragma unroll
      for (int r = 0; r < 4; ++r) {
        int row = base + lg * 4 + r;
        if (row < N) {
          if (nt < 8) {
            int o = swz(nt * 16 + li);
            s2[(size_t)row * 128 + o] = acc[nt][r] + breg[nt];
          } else {
            int o = swz((nt - 8) * 16 + li);
            g2[(size_t)row * 128 + o] = f2bf(acc[nt][r]);
          }
        }
      }
  } else {
    // ---- scatter: 4 threads per edge
    int gt = (b - SGB) * 256 + threadIdx.x;
    int e = gt >> 2, part = gt & 3;
    if (e < E) {
      int is64 = detect64(ei);
      int r = load_idx(ei, e, is64);
      int c = load_idx(ei, (long long)E + e, is64);
      int pos = row_ptr[r] + rank[e];
      if (MODE == 0) {
        f32x4 a0 = *(const f32x4*)(ef + (size_t)e * ED + part * 8);
        f32x4 a1 = *(const f32x4*)(ef + (size_t)e * ED + part * 8 + 4);
        bf16x8 ob;
        #pragma unroll
        for (int j = 0; j < 4; ++j) { ob[j] = f2bf(a0[j]); ob[4 + j] = f2bf(a1[j]); }
        *(bf16x8*)(efb + (size_t)pos * ED + part * 8) = ob;
        if (part == 0) ccol[pos] = c;
      } else {
        if (part == 0) ec[pos] = make_int2(e, c);
      }
    }
  }
}

// --- layer 1 + segment reduce: 2 waves/node (64 cols each), streamed efb ---
template <int MODE>
__global__ __launch_bounds__(128, 4) void layer1_kernel(
    const float* __restrict__ s2, const short* __restrict__ g2,
    const short* __restrict__ efb, const float* __restrict__ ef,
    const int* __restrict__ ccol, const int2* __restrict__ ec,
    const short* __restrict__ w1eA, const int* __restrict__ row_ptr,
    float* __restrict__ hsum) {
  int node = blockIdx.x;
  int lane = threadIdx.x & 63;
  int w = threadIdx.x >> 6;  // col half 0/1
  int li = lane & 15, lg = lane >> 4;
  int rp = row_ptr[node], rpe = row_ptr[node + 1];
  int deg = rpe - rp;

  if (deg == 0) {
    if (li == 0) {
      #pragma unroll
      for (int nt = 0; nt < 4; ++nt)
        *(f32x4*)(hsum + (size_t)node * 128 + (w * 4 + nt) * 16 + lg * 4) =
            (f32x4){0.f, 0.f, 0.f, 0.f};
    }
    return;
  }

  bf16x8 wa[4];
  #pragma unroll
  for (int nt = 0; nt < 4; ++nt)
    wa[nt] = *(const bf16x8*)(w1eA + ((w * 4 + nt) * 64 + lane) * 8);
  f32x4 sreg[4];
  #pragma unroll
  for (int nt = 0; nt < 4; ++nt)
    sreg[nt] = *(const f32x4*)(s2 + (size_t)node * 128 + w * 64 + lg * 16 + nt * 4);
  f32x4 psum[4];
  #pragma unroll
  for (int nt = 0; nt < 4; ++nt) psum[nt] = (f32x4){0.f, 0.f, 0.f, 0.f};

  int ntiles = (deg + 15) >> 4;
  int last = rpe - 1;
  auto ppos = [&](int t) {
    int p = rp + t * 16 + li;
    return p > last ? last : p;
  };

  if (MODE == 0) {
    int p0 = ppos(0), p1 = ppos(1);
    int c0 = ccol[p0], c1 = ccol[p1];
    bf16x8 bf0 = *(const bf16x8*)(efb + (size_t)p0 * ED + lg * 8);
    bf16x8 bf1 = *(const bf16x8*)(efb + (size_t)p1 * ED + lg * 8);
    bf16x8 ga = *(const bf16x8*)(g2 + (size_t)c0 * 128 + w * 64 + lg * 16);
    bf16x8 gb = *(const bf16x8*)(g2 + (size_t)c0 * 128 + w * 64 + lg * 16 + 8);
    for (int t = 0; t < ntiles; ++t) {
      int p2 = ppos(t + 2);
      int c2 = ccol[p2];
      bf16x8 bf2 = *(const bf16x8*)(efb + (size_t)p2 * ED + lg * 8);
      bf16x8 gan = *(const bf16x8*)(g2 + (size_t)c1 * 128 + w * 64 + lg * 16);
      bf16x8 gbn = *(const bf16x8*)(g2 + (size_t)c1 * 128 + w * 64 + lg * 16 + 8);
      f32x4 a0 = __builtin_amdgcn_mfma_f32_16x16x32_bf16(wa[0], bf0, (f32x4){0.f,0.f,0.f,0.f}, 0, 0, 0);
      f32x4 a1 = __builtin_amdgcn_mfma_f32_16x16x32_bf16(wa[1], bf0, (f32x4){0.f,0.f,0.f,0.f}, 0, 0, 0);
      f32x4 a2 = __builtin_amdgcn_mfma_f32_16x16x32_bf16(wa[2], bf0, (f32x4){0.f,0.f,0.f,0.f}, 0, 0, 0);
      f32x4 a3 = __builtin_amdgcn_mfma_f32_16x16x32_bf16(wa[3], bf0, (f32x4){0.f,0.f,0.f,0.f}, 0, 0, 0);
      if ((t * 16 + li) < deg) {
        f32x4 v0 = a0 + sreg[0] + bf8lo(ga);
        f32x4 v1 = a1 + sreg[1] + bf8hi(ga);
        f32x4 v2 = a2 + sreg[2] + bf8lo(gb);
        f32x4 v3 = a3 + sreg[3] + bf8hi(gb);
        #pragma unroll
        for (int r = 0; r < 4; ++r) {
          psum[0][r] += (v0[r] > 0.f ? v0[r] : 0.f);
          psum[1][r] += (v1[r] > 0.f ? v1[r] : 0.f);
          psum[2][r] += (v2[r] > 0.f ? v2[r] : 0.f);
          psum[3][r] += (v3[r] > 0.f ? v3[r] : 0.f);
        }
      }
      c0 = c1; c1 = c2; bf0 = bf1; bf1 = bf2; ga = gan; gb = gbn;
    }
  } else {
    int2 i0 = ec[ppos(0)], i1 = ec[ppos(1)];
    f32x4 e0 = *(const f32x4*)(ef + (size_t)i0.x * ED + lg * 8);
    f32x4 e1 = *(const f32x4*)(ef + (size_t)i0.x * ED + lg * 8 + 4);
    bf16x8 ga = *(const bf16x8*)(g2 + (size_t)i0.y * 128 + w * 64 + lg * 16);
    bf16x8 gb = *(const bf16x8*)(g2 + (size_t)i0.y * 128 + w * 64 + lg * 16 + 8);
    for (int t = 0; t < ntiles; ++t) {
      int2 i2 = ec[ppos(t + 2)];
      f32x4 e0n = *(const f32x4*)(ef + (size_t)i1.x * ED + lg * 8);
      f32x4 e1n = *(const f32x4*)(ef + (size_t)i1.x * ED + lg * 8 + 4);
      bf16x8 gan = *(const bf16x8*)(g2 + (size_t)i1.y * 128 + w * 64 + lg * 16);
      bf16x8 gbn = *(const bf16x8*)(g2 + (size_t)i1.y * 128 + w * 64 + lg * 16 + 8);
      bf16x8 bf;
      #pragma unroll
      for (int j = 0; j < 4; ++j) { bf[j] = f2bf(e0[j]); bf[4 + j] = f2bf(e1[j]); }
      f32x4 a0 = __builtin_amdgcn_mfma_f32_16x16x32_bf16(wa[0], bf, (f32x4){0.f,0.f,0.f,0.f}, 0, 0, 0);
      f32x4 a1 = __builtin_amdgcn_mfma_f32_16x16x32_bf16(wa[1], bf, (f32x4){0.f,0.f,0.f,0.f}, 0, 0, 0);
      f32x4 a2 = __builtin_amdgcn_mfma_f32_16x16x32_bf16(wa[2], bf, (f32x4){0.f,0.f,0.f,0.f}, 0, 0, 0);
      f32x4 a3 = __builtin_amdgcn_mfma_f32_16x16x32_bf16(wa[3], bf, (f32x4){0.f,0.f,0.f,0.f}, 0, 0, 0);
      if ((t * 16 + li) < deg) {
        f32x4 v0 = a0 + sreg[0] + bf8lo(ga);
        f32x4 v1 = a1 + sreg[1] + bf8hi(ga);
        f32x4 v2 = a2 + sreg[2] + bf8lo(gb);
        f32x4 v3 = a3 + sreg[3] + bf8hi(gb);
        #pragma unroll
        for (int r = 0; r < 4; ++r) {
          psum[0][r] += (v0[r] > 0.f ? v0[r] : 0.f);
          psum[1][r] += (v1[r] > 0.f ? v1[r] : 0.f);
          psum[2][r] += (v2[r] > 0.f ? v2[r] : 0.f);
          psum[3][r] += (v3[r] > 0.f ? v3[r] : 0.f);
        }
      }
      i0 = i1; i1 = i2; e0 = e0n; e1 = e1n; ga = gan; gb = gbn;
    }
  }

  #pragma unroll
  for (int nt = 0; nt < 4; ++nt)
    #pragma unroll
    for (int r = 0; r < 4; ++r) {
      float v = psum[nt][r];
      v += __shfl_xor(v, 1);
      v += __shfl_xor(v, 2);
      v += __shfl_xor(v, 4);
      v += __shfl_xor(v, 8);
      psum[nt][r] = v;
    }
  if (li == 0) {
    #pragma unroll
    for (int nt = 0; nt < 4; ++nt)
      *(f32x4*)(hsum + (size_t)node * 128 + (w * 4 + nt) * 16 + lg * 4) = psum[nt];
  }
}

// --- out = Hsum @ W2 + deg*b2 ; 4 waves x 16 rows per block ---
__global__ __launch_bounds__(256) void out_kernel(const float* __restrict__ hsum,
                                                  const short* __restrict__ w2t,
                                                  const float* __restrict__ b2,
                                                  const int* __restrict__ row_ptr,
                                                  float* __restrict__ out, int N) {
  int lane = threadIdx.x & 63, w = threadIdx.x >> 6;
  int li = lane & 15, lg = lane >> 4;
  int base = blockIdx.x * 64 + w * 16;
  int rowm = base + li;
  if (rowm >= N) rowm = N - 1;
  float breg[8];
  #pragma unroll
  for (int nt = 0; nt < 8; ++nt) breg[nt] = b2[nt * 16 + li];
  f32x4 acc[8];
  #pragma unroll
  for (int nt = 0; nt < 8; ++nt) acc[nt] = (f32x4){0.f, 0.f, 0.f, 0.f};
  #pragma unroll
  for (int kc = 0; kc < 4; ++kc) {
    f32x4 f0 = *(const f32x4*)(hsum + (size_t)rowm * 128 + kc * 32 + lg * 8);
    f32x4 f1 = *(const f32x4*)(hsum + (size_t)rowm * 128 + kc * 32 + lg * 8 + 4);
    bf16x8 a;
    #pragma unroll
    for (int j = 0; j < 4; ++j) { a[j] = f2bf(f0[j]); a[4 + j] = f2bf(f1[j]); }
    #pragma unroll
    for (int nt = 0; nt < 8; ++nt) {
      bf16x8 bb = *(const bf16x8*)(w2t + (nt * 16 + li) * 128 + kc * 32 + lg * 8);
      acc[nt] = __builtin_amdgcn_mfma_f32_16x16x32_bf16(a, bb, acc[nt], 0, 0, 0);
    }
  }
  #pragma unroll
  for (int r = 0; r < 4; ++r) {
    int row = base + lg * 4 + r;
    if (row < N) {
      float dg = (float)(row_ptr[row + 1] - row_ptr[row]);
      #pragma unroll
      for (int nt = 0; nt < 8; ++nt)
        out[(size_t)row * 128 + nt * 16 + li] = acc[nt][r] + dg * breg[nt];
    }
  }
}

extern "C" void kernel_launch(void* const* d_in, const int* in_sizes, int n_in,
                              void* d_out, int out_size, void* d_ws, size_t ws_size,
                              hipStream_t stream) {
  const float* h  = (const float*)d_in[0];
  const void*  ei = d_in[1];
  const float* ef = (const float*)d_in[2];
  const float* W1 = (const float*)d_in[4];
  const float* b1 = (const float*)d_in[5];
  const float* W2 = (const float*)d_in[6];
  const float* b2 = (const float*)d_in[7];
  float* out = (float*)d_out;
  int N = in_sizes[0] / ND;
  int E = in_sizes[2] / ED;

  char* ws = (char*)d_ws;
  size_t off = 0;
  auto alloc = [&](size_t bytes) {
    size_t o = off;
    off = (off + bytes + 255) & ~(size_t)255;
    return o;
  };
  int*   counts  = (int*)(ws + alloc((size_t)N * 4));
  int*   row_ptr = (int*)(ws + alloc((size_t)(N + 1) * 4));
  int*   rank    = (int*)(ws + alloc((size_t)E * 4));
  short* w12t    = (short*)(ws + alloc(256 * 128 * 2));
  short* w1eA    = (short*)(ws + alloc(8 * 64 * 8 * 2));
  short* w2t     = (short*)(ws + alloc(128 * 128 * 2));
  float* s2      = (float*)(ws + alloc((size_t)N * 128 * 4));
  short* g2      = (short*)(ws + alloc((size_t)N * 128 * 2));
  float* hsumb   = (float*)(ws + alloc((size_t)N * 128 * 4));
  size_t branch_off = off;
  // MODE 0 layout
  short* efb  = (short*)(ws + branch_off);
  int*   ccol = (int*)(ws + ((branch_off + (size_t)E * ED * 2 + 255) & ~(size_t)255));
  size_t need0 = ((branch_off + (size_t)E * ED * 2 + 255) & ~(size_t)255) + (size_t)E * 4;
  // MODE 1 layout
  int2* ec = (int2*)(ws + branch_off);
  size_t need1 = branch_off + (size_t)E * 8;
  int mode = (ws_size >= need0) ? 0 : 1;
  (void)need1;

  int SGB = (N + 63) >> 6;
  int SCB = (4 * E + 255) / 256;

  hipMemsetAsync(counts, 0, (size_t)N * 4, stream);
  prep_hist_kernel<<<128 + (E + 255) / 256, 256, 0, stream>>>(
      W1, W2, ei, counts, rank, w12t, w1eA, w2t, E);
  scan_kernel<<<1, 1024, 0, stream>>>(counts, row_ptr, N);
  if (mode == 0) {
    scatter_sg_kernel<0><<<SGB + SCB, 256, 0, stream>>>(
        ei, ef, row_ptr, rank, h, w12t, b1, efb, ccol, ec, s2, g2, N, E);
    layer1_kernel<0><<<N, 128, 0, stream>>>(s2, g2, efb, ef, ccol, ec, w1eA, row_ptr, hsumb);
  } else {
    scatter_sg_kernel<1><<<SGB + SCB, 256, 0, stream>>>(
        ei, ef, row_ptr, rank, h, w12t, b1, efb, ccol, ec, s2, g2, N, E);
    layer1_kernel<1><<<N, 128, 0, stream>>>(s2, g2, efb, ef, ccol, ec, w1eA, row_ptr, hsumb);
  }
  out_kernel<<<(N + 63) / 64, 256, 0, stream>>>(hsumb, w2t, b2, row_ptr, out, N);
}